// Round 1
// baseline (855.902 us; speedup 1.0000x reference)
//
#include <hip/hip_runtime.h>
#include <hip/hip_bf16.h>

typedef unsigned short u16;
typedef unsigned int u32;
typedef __attribute__((ext_vector_type(8))) short short8;
typedef __attribute__((ext_vector_type(4))) float f32x4;

__device__ __forceinline__ u16 f2bf(float x) {
  __hip_bfloat16 h = __float2bfloat16(x);
  return *reinterpret_cast<u16*>(&h);
}
__device__ __forceinline__ float bflo(u32 u) { return __uint_as_float(u << 16); }
__device__ __forceinline__ float bfhi(u32 u) { return __uint_as_float(u & 0xffff0000u); }

// ---------------- weight transpose + cast: dst[n*K+k] = bf16(src[k*N+n]) ----------------
__global__ void k_wprep(const float* __restrict__ src, u16* __restrict__ dst, int K, int N) {
  int idx = blockIdx.x * 256 + threadIdx.x;
  if (idx >= K * N) return;
  int k = idx / N, n = idx - k * N;
  dst[n * K + k] = f2bf(src[idx]);
}

// ---------------- LN1 + roll(-2) + window partition -> bf16 [262144][128] ----------------
__global__ __launch_bounds__(256) void k_ln1(const float* __restrict__ in,
                                             const float* __restrict__ g1,
                                             const float* __restrict__ b1,
                                             u16* __restrict__ lnb) {
  int lane = threadIdx.x & 63;
  size_t o = (size_t)blockIdx.x * 4 + (threadIdx.x >> 6);
  int n = (int)(o & 63), wbox = (int)((o >> 6) & 511), b = (int)(o >> 15);
  int gx = wbox >> 6, gy = (wbox >> 3) & 7, gz = wbox & 7;
  int ix = n >> 4, iy = (n >> 2) & 3, iz = n & 3;
  int X = (gx * 4 + ix + 2) & 31, Y = (gy * 4 + iy + 2) & 31, Z = (gz * 4 + iz + 2) & 31;
  const float* row = in + (((size_t)b << 15) + (size_t)(X * 1024 + Y * 32 + Z)) * 128;
  float x0 = row[lane], x1 = row[lane + 64];
  float s = x0 + x1, ss = x0 * x0 + x1 * x1;
  #pragma unroll
  for (int off = 32; off > 0; off >>= 1) {
    s += __shfl_xor(s, off, 64);
    ss += __shfl_xor(ss, off, 64);
  }
  float mean = s * 0.0078125f;
  float var = ss * 0.0078125f - mean * mean;
  float rs = rsqrtf(var + 1e-5f);
  lnb[o * 128 + lane]      = f2bf((x0 - mean) * rs * g1[lane] + b1[lane]);
  lnb[o * 128 + lane + 64] = f2bf((x1 - mean) * rs * g1[lane + 64] + b1[lane + 64]);
}

// ---------------- shared 64x128-tile MFMA core: A_s [64][136], B_s(=W^T) [128][136] ----------------
__device__ __forceinline__ void mfma_64x128(const u16* A_s, const u16* B_s,
                                            f32x4 acc[2][4], int wid, int lane) {
  const int m = lane & 15, kg = lane >> 4;
  const int ro = (wid & 1) * 32, co = (wid >> 1) * 64;
  #pragma unroll
  for (int kc = 0; kc < 4; ++kc) {
    short8 a[2], b[4];
    #pragma unroll
    for (int tm = 0; tm < 2; ++tm)
      a[tm] = *(const short8*)(A_s + (ro + tm * 16 + m) * 136 + kc * 32 + kg * 8);
    #pragma unroll
    for (int tn = 0; tn < 4; ++tn)
      b[tn] = *(const short8*)(B_s + (co + tn * 16 + m) * 136 + kc * 32 + kg * 8);
    #pragma unroll
    for (int tm = 0; tm < 2; ++tm)
      #pragma unroll
      for (int tn = 0; tn < 4; ++tn)
        acc[tm][tn] = __builtin_amdgcn_mfma_f32_16x16x32_bf16(a[tm], b[tn], acc[tm][tn], 0, 0, 0);
  }
}

// ---------------- QKV GEMM: [T,128] x [128,384] -> bf16 qkv [T][384], q pre-scaled ----------------
__global__ __launch_bounds__(256) void k_qkv(const u16* __restrict__ lnb,
                                             const u16* __restrict__ wT,
                                             u16* __restrict__ qkv) {
  __shared__ __align__(16) u16 A_s[64 * 136];
  __shared__ __align__(16) u16 B_s[128 * 136];
  const int t = threadIdx.x, wid = t >> 6, lane = t & 63;
  const size_t mbase = (size_t)blockIdx.x * 64;
  const int n0 = blockIdx.y * 128;
  {
    int r = t >> 2, seg = t & 3;
    const short8* src = (const short8*)(lnb + (mbase + r) * 128 + seg * 32);
    short8* dst = (short8*)(A_s + r * 136 + seg * 32);
    #pragma unroll
    for (int i = 0; i < 4; ++i) dst[i] = src[i];
  }
  {
    int r = t >> 1, half = t & 1;
    const short8* src = (const short8*)(wT + (size_t)(n0 + r) * 128 + half * 64);
    short8* dst = (short8*)(B_s + r * 136 + half * 64);
    #pragma unroll
    for (int i = 0; i < 8; ++i) dst[i] = src[i];
  }
  __syncthreads();
  f32x4 zero = {0.f, 0.f, 0.f, 0.f};
  f32x4 acc[2][4];
  #pragma unroll
  for (int tm = 0; tm < 2; ++tm)
    #pragma unroll
    for (int tn = 0; tn < 4; ++tn) acc[tm][tn] = zero;
  mfma_64x128(A_s, B_s, acc, wid, lane);
  const int m = lane & 15, kg = lane >> 4;
  const int ro = (wid & 1) * 32, co = (wid >> 1) * 64;
  #pragma unroll
  for (int tm = 0; tm < 2; ++tm)
    #pragma unroll
    for (int tn = 0; tn < 4; ++tn)
      #pragma unroll
      for (int r = 0; r < 4; ++r) {
        int row = ro + tm * 16 + kg * 4 + r;
        int cc = n0 + co + tn * 16 + m;
        float v = acc[tm][tn][r];
        if (cc < 128) v *= 0.17677669529663687f;   // q * HD^-0.5
        qkv[(mbase + row) * 384 + cc] = f2bf(v);
      }
}

// ---------------- per-window attention: block=window, wave=head ----------------
__global__ __launch_bounds__(256) void k_attn(const u16* __restrict__ qkv,
                                              const float* __restrict__ btab,
                                              u16* __restrict__ att) {
  __shared__ float K_s[4][64][32];
  __shared__ u16 V_s[4][64][32];
  __shared__ float bias_s[484];
  const int t = threadIdx.x;
  const int bw = blockIdx.x;
  const size_t base = (size_t)bw * 64;
  const int wbox = bw & 511;
  const int gx = wbox >> 6, gy = (wbox >> 3) & 7, gz = wbox & 7;
  for (int i = t; i < 484; i += 256) bias_s[i] = btab[i];
  #pragma unroll
  for (int i = 0; i < 16; ++i) {
    int flatu = i * 256 + t;
    int nn = flatu >> 6;
    int ch = (flatu & 63) * 2;
    int hh = ch >> 5, d = ch & 31;
    u32 kv = *(const u32*)(qkv + (base + nn) * 384 + 128 + ch);
    K_s[hh][nn][d] = bflo(kv);
    K_s[hh][nn][d + 1] = bfhi(kv);
    u32 vv = *(const u32*)(qkv + (base + nn) * 384 + 256 + ch);
    *(u32*)&V_s[hh][nn][d] = vv;
  }
  __syncthreads();
  const int h = t >> 6, n = t & 63;
  const int ix = n >> 4, iy = (n >> 2) & 3, iz = n & 3;
  float q[32];
  const u32* q32 = (const u32*)(qkv + (base + n) * 384 + h * 32);
  #pragma unroll
  for (int du = 0; du < 16; ++du) { u32 u = q32[du]; q[2 * du] = bflo(u); q[2 * du + 1] = bfhi(u); }
  int catx[4], caty[4], catz[4];
  #pragma unroll
  for (int a = 0; a < 4; ++a) {
    catx[a] = (gx < 7) ? 0 : ((a < 2) ? 1 : 2);
    caty[a] = (gy < 7) ? 0 : ((a < 2) ? 1 : 2);
    catz[a] = (gz < 7) ? 0 : ((a < 2) ? 1 : 2);
  }
  const int labn = catx[ix] * 9 + caty[iy] * 3 + catz[iz];
  float S[64];
  #pragma unroll
  for (int j = 0; j < 64; ++j) {
    const float4* kj = (const float4*)K_s[h][j];
    float a = 0.f;
    #pragma unroll
    for (int c4 = 0; c4 < 8; ++c4) {
      float4 kv = kj[c4];
      a += q[c4 * 4] * kv.x + q[c4 * 4 + 1] * kv.y + q[c4 * 4 + 2] * kv.z + q[c4 * 4 + 3] * kv.w;
    }
    int jx = j >> 4, jy = (j >> 2) & 3, jz = j & 3;
    a += bias_s[(11 * (ix - jx + 3) + (iy - jy + 3) + (iz - jz + 3)) * 4 + h];
    int labj = catx[jx] * 9 + caty[jy] * 3 + catz[jz];
    S[j] = (labj == labn) ? a : (a - 100.f);
  }
  float mx = -1e30f;
  #pragma unroll
  for (int j = 0; j < 64; ++j) mx = fmaxf(mx, S[j]);
  float sum = 0.f;
  #pragma unroll
  for (int j = 0; j < 64; ++j) { float e = __expf(S[j] - mx); S[j] = e; sum += e; }
  const float inv = 1.f / sum;
  float O[32];
  #pragma unroll
  for (int d = 0; d < 32; ++d) O[d] = 0.f;
  #pragma unroll
  for (int j = 0; j < 64; ++j) {
    float p = S[j];
    const uint4* vj = (const uint4*)V_s[h][j];
    #pragma unroll
    for (int c4 = 0; c4 < 4; ++c4) {
      uint4 u = vj[c4];
      O[c4 * 8 + 0] += p * bflo(u.x); O[c4 * 8 + 1] += p * bfhi(u.x);
      O[c4 * 8 + 2] += p * bflo(u.y); O[c4 * 8 + 3] += p * bfhi(u.y);
      O[c4 * 8 + 4] += p * bflo(u.z); O[c4 * 8 + 5] += p * bfhi(u.z);
      O[c4 * 8 + 6] += p * bflo(u.w); O[c4 * 8 + 7] += p * bfhi(u.w);
    }
  }
  u32* orow = (u32*)(att + (base + n) * 128 + h * 32);
  #pragma unroll
  for (int du = 0; du < 16; ++du)
    orow[du] = (u32)f2bf(O[2 * du] * inv) | ((u32)f2bf(O[2 * du + 1] * inv) << 16);
}

// ---------------- proj GEMM + reverse-partition/unshift scatter + 0.5*out + inputs -> x (fp32) ----------------
__global__ __launch_bounds__(256) void k_proj(const u16* __restrict__ att,
                                              const u16* __restrict__ wT,
                                              const float* __restrict__ proj_b,
                                              const float* __restrict__ inputs,
                                              float* __restrict__ xws) {
  __shared__ __align__(16) u16 A_s[64 * 136];
  __shared__ __align__(16) u16 B_s[128 * 136];
  const int t = threadIdx.x, wid = t >> 6, lane = t & 63;
  const size_t mbase = (size_t)blockIdx.x * 64;
  {
    int r = t >> 2, seg = t & 3;
    const short8* src = (const short8*)(att + (mbase + r) * 128 + seg * 32);
    short8* dst = (short8*)(A_s + r * 136 + seg * 32);
    #pragma unroll
    for (int i = 0; i < 4; ++i) dst[i] = src[i];
  }
  {
    int r = t >> 1, half = t & 1;
    const short8* src = (const short8*)(wT + (size_t)r * 128 + half * 64);
    short8* dst = (short8*)(B_s + r * 136 + half * 64);
    #pragma unroll
    for (int i = 0; i < 8; ++i) dst[i] = src[i];
  }
  __syncthreads();
  f32x4 zero = {0.f, 0.f, 0.f, 0.f};
  f32x4 acc[2][4];
  #pragma unroll
  for (int tm = 0; tm < 2; ++tm)
    #pragma unroll
    for (int tn = 0; tn < 4; ++tn) acc[tm][tn] = zero;
  mfma_64x128(A_s, B_s, acc, wid, lane);
  const int m = lane & 15, kg = lane >> 4;
  const int ro = (wid & 1) * 32, co = (wid >> 1) * 64;
  #pragma unroll
  for (int tm = 0; tm < 2; ++tm)
    #pragma unroll
    for (int r = 0; r < 4; ++r) {
      int row = ro + tm * 16 + kg * 4 + r;
      size_t o = mbase + row;
      int nn = (int)(o & 63), wbox = (int)((o >> 6) & 511), bb = (int)(o >> 15);
      int gx = wbox >> 6, gy = (wbox >> 3) & 7, gz = wbox & 7;
      int ix = nn >> 4, iy = (nn >> 2) & 3, iz = nn & 3;
      int X = (gx * 4 + ix + 2) & 31, Y = (gy * 4 + iy + 2) & 31, Z = (gz * 4 + iz + 2) & 31;
      size_t orig = ((size_t)bb << 15) + (size_t)(X * 1024 + Y * 32 + Z);
      #pragma unroll
      for (int tn = 0; tn < 4; ++tn) {
        int col = co + tn * 16 + m;
        float v = acc[tm][tn][r] + proj_b[col];
        xws[orig * 128 + col] = 0.5f * v + inputs[orig * 128 + col];
      }
    }
}

// ---------------- fused LN2 + MLP (128->512 GELU ->128) + 0.5*h + x -> out ----------------
__global__ __launch_bounds__(256) void k_mlp(const float* __restrict__ x,
                                             const u16* __restrict__ w1T,
                                             const u16* __restrict__ w2T,
                                             const float* __restrict__ g2,
                                             const float* __restrict__ b2,
                                             const float* __restrict__ bb1,
                                             const float* __restrict__ bb2,
                                             float* __restrict__ out) {
  __shared__ __align__(16) u16 A_s[64 * 136];
  __shared__ __align__(16) u16 B1_s[64 * 136];
  __shared__ __align__(16) u16 H_s[64 * 72];
  __shared__ __align__(16) u16 B2_s[128 * 72];
  __shared__ float red[64][8];
  const int t = threadIdx.x, wid = t >> 6, lane = t & 63;
  const size_t mbase = (size_t)blockIdx.x * 64;
  {
    int r = t >> 2, seg = t & 3;
    const float4* x4 = (const float4*)(x + (mbase + r) * 128 + seg * 32);
    float vals[32];
    float s = 0.f, ss = 0.f;
    #pragma unroll
    for (int i = 0; i < 8; ++i) {
      float4 v = x4[i];
      vals[4 * i] = v.x; vals[4 * i + 1] = v.y; vals[4 * i + 2] = v.z; vals[4 * i + 3] = v.w;
      s += v.x + v.y + v.z + v.w;
      ss += v.x * v.x + v.y * v.y + v.z * v.z + v.w * v.w;
    }
    red[r][seg] = s; red[r][4 + seg] = ss;
    __syncthreads();
    float sum = red[r][0] + red[r][1] + red[r][2] + red[r][3];
    float sq = red[r][4] + red[r][5] + red[r][6] + red[r][7];
    float mean = sum * 0.0078125f;
    float var = sq * 0.0078125f - mean * mean;
    float rs = rsqrtf(var + 1e-5f);
    #pragma unroll
    for (int i = 0; i < 32; ++i) {
      int c = seg * 32 + i;
      A_s[r * 136 + c] = f2bf((vals[i] - mean) * rs * g2[c] + b2[c]);
    }
  }
  const int m = lane & 15, kg = lane >> 4;
  const int ro = (wid & 1) * 32;
  const int co2 = (wid >> 1) * 32;
  const int co = (wid >> 1) * 64;
  f32x4 zero = {0.f, 0.f, 0.f, 0.f};
  f32x4 acc[2][4];
  #pragma unroll
  for (int tm = 0; tm < 2; ++tm)
    #pragma unroll
    for (int tn = 0; tn < 4; ++tn) acc[tm][tn] = zero;
  for (int nt = 0; nt < 8; ++nt) {
    __syncthreads();
    {
      int r = t >> 2, seg = t & 3;
      const short8* src = (const short8*)(w1T + (size_t)(nt * 64 + r) * 128 + seg * 32);
      short8* dst = (short8*)(B1_s + r * 136 + seg * 32);
      #pragma unroll
      for (int i = 0; i < 4; ++i) dst[i] = src[i];
    }
    {
      int r = t >> 1, half = t & 1;
      const short8* src = (const short8*)(w2T + (size_t)r * 512 + nt * 64 + half * 32);
      short8* dst = (short8*)(B2_s + r * 72 + half * 32);
      #pragma unroll
      for (int i = 0; i < 4; ++i) dst[i] = src[i];
    }
    __syncthreads();
    f32x4 hacc[2][2];
    #pragma unroll
    for (int tm = 0; tm < 2; ++tm)
      #pragma unroll
      for (int tn = 0; tn < 2; ++tn) hacc[tm][tn] = zero;
    #pragma unroll
    for (int kc = 0; kc < 4; ++kc) {
      short8 a[2], b[2];
      #pragma unroll
      for (int tm = 0; tm < 2; ++tm)
        a[tm] = *(const short8*)(A_s + (ro + tm * 16 + m) * 136 + kc * 32 + kg * 8);
      #pragma unroll
      for (int tn = 0; tn < 2; ++tn)
        b[tn] = *(const short8*)(B1_s + (co2 + tn * 16 + m) * 136 + kc * 32 + kg * 8);
      #pragma unroll
      for (int tm = 0; tm < 2; ++tm)
        #pragma unroll
        for (int tn = 0; tn < 2; ++tn)
          hacc[tm][tn] = __builtin_amdgcn_mfma_f32_16x16x32_bf16(a[tm], b[tn], hacc[tm][tn], 0, 0, 0);
    }
    #pragma unroll
    for (int tm = 0; tm < 2; ++tm)
      #pragma unroll
      for (int tn = 0; tn < 2; ++tn)
        #pragma unroll
        for (int r = 0; r < 4; ++r) {
          int row = ro + tm * 16 + kg * 4 + r;
          int col = co2 + tn * 16 + m;
          float v = hacc[tm][tn][r] + bb1[nt * 64 + col];
          v = 0.5f * v * (1.f + erff(v * 0.7071067811865475f));
          H_s[row * 72 + col] = f2bf(v);
        }
    __syncthreads();
    #pragma unroll
    for (int kc = 0; kc < 2; ++kc) {
      short8 a[2], b[4];
      #pragma unroll
      for (int tm = 0; tm < 2; ++tm)
        a[tm] = *(const short8*)(H_s + (ro + tm * 16 + m) * 72 + kc * 32 + kg * 8);
      #pragma unroll
      for (int tn = 0; tn < 4; ++tn)
        b[tn] = *(const short8*)(B2_s + (co + tn * 16 + m) * 72 + kc * 32 + kg * 8);
      #pragma unroll
      for (int tm = 0; tm < 2; ++tm)
        #pragma unroll
        for (int tn = 0; tn < 4; ++tn)
          acc[tm][tn] = __builtin_amdgcn_mfma_f32_16x16x32_bf16(a[tm], b[tn], acc[tm][tn], 0, 0, 0);
    }
  }
  #pragma unroll
  for (int tm = 0; tm < 2; ++tm)
    #pragma unroll
    for (int tn = 0; tn < 4; ++tn)
      #pragma unroll
      for (int r = 0; r < 4; ++r) {
        int row = ro + tm * 16 + kg * 4 + r;
        int col = co + tn * 16 + m;
        size_t tok = mbase + row;
        float v = acc[tm][tn][r] + bb2[col];
        out[tok * 128 + col] = 0.5f * v + x[tok * 128 + col];
      }
}

extern "C" void kernel_launch(void* const* d_in, const int* in_sizes, int n_in,
                              void* d_out, int out_size, void* d_ws, size_t ws_size,
                              hipStream_t stream) {
  const float* inputs = (const float*)d_in[0];
  const float* qkv_w  = (const float*)d_in[1];
  const float* proj_w = (const float*)d_in[2];
  const float* proj_b = (const float*)d_in[3];
  const float* btab   = (const float*)d_in[4];
  const float* g1     = (const float*)d_in[5];
  const float* b1     = (const float*)d_in[6];
  const float* g2     = (const float*)d_in[7];
  const float* b2     = (const float*)d_in[8];
  const float* w1     = (const float*)d_in[9];
  const float* bb1    = (const float*)d_in[10];
  const float* w2     = (const float*)d_in[11];
  const float* bb2    = (const float*)d_in[12];
  float* out = (float*)d_out;

  char* ws = (char*)d_ws;
  u16* qkvT  = (u16*)(ws + 0);          // 384*128 bf16
  u16* projT = (u16*)(ws + 98304);      // 128*128
  u16* w1T   = (u16*)(ws + 131072);     // 512*128
  u16* w2T   = (u16*)(ws + 262144);     // 128*512
  u16* lnb   = (u16*)(ws + 393216);     // T*128 bf16 (reused as attn_out)
  u16* qkv   = (u16*)(ws + 393216 + 67108864);  // T*384 bf16 (reused as x fp32)
  u16* att   = lnb;                     // overlay: lnb dead after k_qkv
  float* xws = (float*)qkv;             // overlay: qkv dead after k_attn

  k_wprep<<<192, 256, 0, stream>>>(qkv_w, qkvT, 128, 384);
  k_wprep<<<64, 256, 0, stream>>>(proj_w, projT, 128, 128);
  k_wprep<<<256, 256, 0, stream>>>(w1, w1T, 128, 512);
  k_wprep<<<256, 256, 0, stream>>>(w2, w2T, 512, 128);

  k_ln1<<<65536, 256, 0, stream>>>(inputs, g1, b1, lnb);
  k_qkv<<<dim3(4096, 3), 256, 0, stream>>>(lnb, qkvT, qkv);
  k_attn<<<4096, 256, 0, stream>>>(qkv, btab, att);
  k_proj<<<4096, 256, 0, stream>>>(att, projT, proj_b, inputs, xws);
  k_mlp<<<4096, 256, 0, stream>>>(xws, w1T, w2T, g2, b2, bb1, bb2, out);
}

// Round 2
// 702.392 us; speedup vs baseline: 1.2186x; 1.2186x over previous
//
#include <hip/hip_runtime.h>
#include <hip/hip_bf16.h>

typedef unsigned short u16;
typedef unsigned int u32;
typedef __attribute__((ext_vector_type(8))) short short8;
typedef __attribute__((ext_vector_type(4))) float f32x4;

__device__ __forceinline__ u16 f2bf(float x) {
  __hip_bfloat16 h = __float2bfloat16(x);
  return *reinterpret_cast<u16*>(&h);
}
__device__ __forceinline__ float bflo(u32 u) { return __uint_as_float(u << 16); }
__device__ __forceinline__ float bfhi(u32 u) { return __uint_as_float(u & 0xffff0000u); }

// ---------------- weight transpose + cast: dst[n*K+k] = bf16(src[k*N+n]) ----------------
__global__ void k_wprep(const float* __restrict__ src, u16* __restrict__ dst, int K, int N) {
  int idx = blockIdx.x * 256 + threadIdx.x;
  if (idx >= K * N) return;
  int k = idx / N, n = idx - k * N;
  dst[n * K + k] = f2bf(src[idx]);
}

// ---------------- LN1 + roll(-2) + window partition -> bf16 [262144][128] ----------------
__global__ __launch_bounds__(256) void k_ln1(const float* __restrict__ in,
                                             const float* __restrict__ g1,
                                             const float* __restrict__ b1,
                                             u16* __restrict__ lnb) {
  int lane = threadIdx.x & 63;
  size_t o = (size_t)blockIdx.x * 4 + (threadIdx.x >> 6);
  int n = (int)(o & 63), wbox = (int)((o >> 6) & 511), b = (int)(o >> 15);
  int gx = wbox >> 6, gy = (wbox >> 3) & 7, gz = wbox & 7;
  int ix = n >> 4, iy = (n >> 2) & 3, iz = n & 3;
  int X = (gx * 4 + ix + 2) & 31, Y = (gy * 4 + iy + 2) & 31, Z = (gz * 4 + iz + 2) & 31;
  const float* row = in + (((size_t)b << 15) + (size_t)(X * 1024 + Y * 32 + Z)) * 128;
  float x0 = row[lane], x1 = row[lane + 64];
  float s = x0 + x1, ss = x0 * x0 + x1 * x1;
  #pragma unroll
  for (int off = 32; off > 0; off >>= 1) {
    s += __shfl_xor(s, off, 64);
    ss += __shfl_xor(ss, off, 64);
  }
  float mean = s * 0.0078125f;
  float var = ss * 0.0078125f - mean * mean;
  float rs = rsqrtf(var + 1e-5f);
  lnb[o * 128 + lane]      = f2bf((x0 - mean) * rs * g1[lane] + b1[lane]);
  lnb[o * 128 + lane + 64] = f2bf((x1 - mean) * rs * g1[lane + 64] + b1[lane + 64]);
}

// ---------------- shared 64x128-tile MFMA core: A_s [64][136], B_s(=W^T) [128][136] ----------------
__device__ __forceinline__ void mfma_64x128(const u16* A_s, const u16* B_s,
                                            f32x4 acc[2][4], int wid, int lane) {
  const int m = lane & 15, kg = lane >> 4;
  const int ro = (wid & 1) * 32, co = (wid >> 1) * 64;
  #pragma unroll
  for (int kc = 0; kc < 4; ++kc) {
    short8 a[2], b[4];
    #pragma unroll
    for (int tm = 0; tm < 2; ++tm)
      a[tm] = *(const short8*)(A_s + (ro + tm * 16 + m) * 136 + kc * 32 + kg * 8);
    #pragma unroll
    for (int tn = 0; tn < 4; ++tn)
      b[tn] = *(const short8*)(B_s + (co + tn * 16 + m) * 136 + kc * 32 + kg * 8);
    #pragma unroll
    for (int tm = 0; tm < 2; ++tm)
      #pragma unroll
      for (int tn = 0; tn < 4; ++tn)
        acc[tm][tn] = __builtin_amdgcn_mfma_f32_16x16x32_bf16(a[tm], b[tn], acc[tm][tn], 0, 0, 0);
  }
}

// ---------------- QKV GEMM: [T,128] x [128,384] -> bf16 qkv [T][384], q pre-scaled ----------------
__global__ __launch_bounds__(256) void k_qkv(const u16* __restrict__ lnb,
                                             const u16* __restrict__ wT,
                                             u16* __restrict__ qkv) {
  __shared__ __align__(16) u16 A_s[64 * 136];
  __shared__ __align__(16) u16 B_s[128 * 136];
  const int t = threadIdx.x, wid = t >> 6, lane = t & 63;
  const size_t mbase = (size_t)blockIdx.x * 64;
  const int n0 = blockIdx.y * 128;
  {
    int r = t >> 2, seg = t & 3;
    const short8* src = (const short8*)(lnb + (mbase + r) * 128 + seg * 32);
    short8* dst = (short8*)(A_s + r * 136 + seg * 32);
    #pragma unroll
    for (int i = 0; i < 4; ++i) dst[i] = src[i];
  }
  {
    int r = t >> 1, half = t & 1;
    const short8* src = (const short8*)(wT + (size_t)(n0 + r) * 128 + half * 64);
    short8* dst = (short8*)(B_s + r * 136 + half * 64);
    #pragma unroll
    for (int i = 0; i < 8; ++i) dst[i] = src[i];
  }
  __syncthreads();
  f32x4 zero = {0.f, 0.f, 0.f, 0.f};
  f32x4 acc[2][4];
  #pragma unroll
  for (int tm = 0; tm < 2; ++tm)
    #pragma unroll
    for (int tn = 0; tn < 4; ++tn) acc[tm][tn] = zero;
  mfma_64x128(A_s, B_s, acc, wid, lane);
  const int m = lane & 15, kg = lane >> 4;
  const int ro = (wid & 1) * 32, co = (wid >> 1) * 64;
  #pragma unroll
  for (int tm = 0; tm < 2; ++tm)
    #pragma unroll
    for (int tn = 0; tn < 4; ++tn)
      #pragma unroll
      for (int r = 0; r < 4; ++r) {
        int row = ro + tm * 16 + kg * 4 + r;
        int cc = n0 + co + tn * 16 + m;
        float v = acc[tm][tn][r];
        if (cc < 128) v *= 0.17677669529663687f;   // q * HD^-0.5
        qkv[(mbase + row) * 384 + cc] = f2bf(v);
      }
}

// ---------------- per-window attention, MFMA version: block=window, wave=head ----------------
// S = Q K^T per head: 64x64, K=32 -> 16 mfma_16x16x32. PV: 64x32, K=64 -> 16 mfma.
// C-layout rows decompose as (ix,iy,iz)=(ti,quad,r); cols as (jx,jy,jz)=(tj,c>>2&3,c&3),
// so rel-pos-bias index and shift-mask labels are pure arithmetic.
__global__ __launch_bounds__(256) void k_attn(const u16* __restrict__ qkv,
                                              const float* __restrict__ btab,
                                              u16* __restrict__ att) {
  __shared__ float bias_s[4][128];               // [h][121] transposed bias table
  __shared__ __align__(16) u16 Vt_s[4][32][72];  // V^T per head: [d][key]
  __shared__ __align__(16) u16 P_s[4][64][72];   // exp(S-m) per head, unnormalized
  const int t = threadIdx.x;
  const int wv = t >> 6, lane = t & 63;
  const int m = lane & 15, q4 = lane >> 4;
  const int bw = blockIdx.x;
  const size_t base = (size_t)bw * 64;
  const int wbox = bw & 511;
  const int gx = wbox >> 6, gy = (wbox >> 3) & 7, gz = wbox & 7;

  // stage bias transposed: bias_s[h][idx] = btab[idx*4+h]
  for (int i = t; i < 484; i += 256) bias_s[i & 3][i >> 2] = btab[i];
  // stage V^T: wave wv covers tokens i*4+wv, lanes cover channel pairs
  #pragma unroll
  for (int i = 0; i < 16; ++i) {
    int nn = i * 4 + wv;
    int ch = lane * 2;
    int hh = ch >> 5, d = ch & 31;
    u32 vv = *(const u32*)(qkv + (base + nn) * 384 + 256 + ch);
    Vt_s[hh][d][nn]     = (u16)(vv & 0xffffu);
    Vt_s[hh][d + 1][nn] = (u16)(vv >> 16);
  }

  // Q / K fragments straight from global (A-layout: row=lane&15, k=quad*8+j)
  short8 qf[4], kf[4];
  #pragma unroll
  for (int ti = 0; ti < 4; ++ti) {
    qf[ti] = *(const short8*)(qkv + (base + ti * 16 + m) * 384 + wv * 32 + q4 * 8);
    kf[ti] = *(const short8*)(qkv + (base + ti * 16 + m) * 384 + 128 + wv * 32 + q4 * 8);
  }

  f32x4 zero = {0.f, 0.f, 0.f, 0.f};
  f32x4 S[4][4];
  #pragma unroll
  for (int ti = 0; ti < 4; ++ti)
    #pragma unroll
    for (int tj = 0; tj < 4; ++tj) S[ti][tj] = zero;

  __syncthreads();   // bias_s / Vt_s visible to all waves

  #pragma unroll
  for (int ti = 0; ti < 4; ++ti)
    #pragma unroll
    for (int tj = 0; tj < 4; ++tj)
      S[ti][tj] = __builtin_amdgcn_mfma_f32_16x16x32_bf16(qf[ti], kf[tj], S[ti][tj], 0, 0, 0);

  // shift-mask labels (all zero for interior windows -> mask vanishes)
  int catx[4], caty[4], catz[4];
  #pragma unroll
  for (int a = 0; a < 4; ++a) {
    catx[a] = (gx < 7) ? 0 : ((a < 2) ? 1 : 2);
    caty[a] = (gy < 7) ? 0 : ((a < 2) ? 1 : 2);
    catz[a] = (gz < 7) ? 0 : ((a < 2) ? 1 : 2);
  }
  const int cy = (m >> 2) & 3, cz = m & 3;
  int labc[4], labr[16];
  #pragma unroll
  for (int tj = 0; tj < 4; ++tj) labc[tj] = catx[tj] * 9 + caty[cy] * 3 + catz[cz];
  #pragma unroll
  for (int ti = 0; ti < 4; ++ti)
    #pragma unroll
    for (int r = 0; r < 4; ++r) labr[ti * 4 + r] = catx[ti] * 9 + caty[q4] * 3 + catz[r];

  // bias + mask (C-layout: row = ti*16 + q4*4 + r, col = tj*16 + m)
  #pragma unroll
  for (int ti = 0; ti < 4; ++ti)
    #pragma unroll
    for (int tj = 0; tj < 4; ++tj) {
      int K0 = 11 * (ti - tj + 3) + (q4 + 3 - cy) + (3 - cz);
      #pragma unroll
      for (int r = 0; r < 4; ++r) {
        float v = S[ti][tj][r] + bias_s[wv][K0 + r];
        if (labr[ti * 4 + r] != labc[tj]) v -= 100.f;
        S[ti][tj][r] = v;
      }
    }

  // softmax over rows: local over tj, then shfl-xor 1/2/4/8 within the 16-lane quad group
  float mx[16], sm[16];
  #pragma unroll
  for (int ti = 0; ti < 4; ++ti)
    #pragma unroll
    for (int r = 0; r < 4; ++r)
      mx[ti * 4 + r] = fmaxf(fmaxf(S[ti][0][r], S[ti][1][r]), fmaxf(S[ti][2][r], S[ti][3][r]));
  #pragma unroll
  for (int off = 1; off < 16; off <<= 1)
    #pragma unroll
    for (int i = 0; i < 16; ++i) mx[i] = fmaxf(mx[i], __shfl_xor(mx[i], off, 64));
  #pragma unroll
  for (int ti = 0; ti < 4; ++ti)
    #pragma unroll
    for (int r = 0; r < 4; ++r) {
      float e0 = __expf(S[ti][0][r] - mx[ti * 4 + r]);
      float e1 = __expf(S[ti][1][r] - mx[ti * 4 + r]);
      float e2 = __expf(S[ti][2][r] - mx[ti * 4 + r]);
      float e3 = __expf(S[ti][3][r] - mx[ti * 4 + r]);
      S[ti][0][r] = e0; S[ti][1][r] = e1; S[ti][2][r] = e2; S[ti][3][r] = e3;
      sm[ti * 4 + r] = (e0 + e1) + (e2 + e3);
    }
  #pragma unroll
  for (int off = 1; off < 16; off <<= 1)
    #pragma unroll
    for (int i = 0; i < 16; ++i) sm[i] += __shfl_xor(sm[i], off, 64);
  #pragma unroll
  for (int i = 0; i < 16; ++i) sm[i] = 1.f / sm[i];   // now holds inv row-sum

  // P (unnormalized exp) -> LDS in row-major A-source layout
  #pragma unroll
  for (int ti = 0; ti < 4; ++ti)
    #pragma unroll
    for (int tj = 0; tj < 4; ++tj)
      #pragma unroll
      for (int r = 0; r < 4; ++r)
        P_s[wv][ti * 16 + q4 * 4 + r][tj * 16 + m] = f2bf(S[ti][tj][r]);

  // O = P V : A-frags from P_s rows, B-frags from Vt_s rows
  f32x4 O[4][2];
  #pragma unroll
  for (int ti = 0; ti < 4; ++ti)
    #pragma unroll
    for (int tv = 0; tv < 2; ++tv) O[ti][tv] = zero;
  #pragma unroll
  for (int ks = 0; ks < 2; ++ks) {
    short8 pa[4], vb[2];
    #pragma unroll
    for (int ti = 0; ti < 4; ++ti)
      pa[ti] = *(const short8*)&P_s[wv][ti * 16 + m][ks * 32 + q4 * 8];
    #pragma unroll
    for (int tv = 0; tv < 2; ++tv)
      vb[tv] = *(const short8*)&Vt_s[wv][tv * 16 + m][ks * 32 + q4 * 8];
    #pragma unroll
    for (int ti = 0; ti < 4; ++ti)
      #pragma unroll
      for (int tv = 0; tv < 2; ++tv)
        O[ti][tv] = __builtin_amdgcn_mfma_f32_16x16x32_bf16(pa[ti], vb[tv], O[ti][tv], 0, 0, 0);
  }

  // epilogue: normalize rows, write att
  #pragma unroll
  for (int ti = 0; ti < 4; ++ti)
    #pragma unroll
    for (int tv = 0; tv < 2; ++tv)
      #pragma unroll
      for (int r = 0; r < 4; ++r) {
        int n = ti * 16 + q4 * 4 + r;
        att[(base + n) * 128 + wv * 32 + tv * 16 + m] = f2bf(O[ti][tv][r] * sm[ti * 4 + r]);
      }
}

// ---------------- proj GEMM + reverse-partition/unshift scatter + 0.5*out + inputs -> x (fp32) ----------------
__global__ __launch_bounds__(256) void k_proj(const u16* __restrict__ att,
                                              const u16* __restrict__ wT,
                                              const float* __restrict__ proj_b,
                                              const float* __restrict__ inputs,
                                              float* __restrict__ xws) {
  __shared__ __align__(16) u16 A_s[64 * 136];
  __shared__ __align__(16) u16 B_s[128 * 136];
  const int t = threadIdx.x, wid = t >> 6, lane = t & 63;
  const size_t mbase = (size_t)blockIdx.x * 64;
  {
    int r = t >> 2, seg = t & 3;
    const short8* src = (const short8*)(att + (mbase + r) * 128 + seg * 32);
    short8* dst = (short8*)(A_s + r * 136 + seg * 32);
    #pragma unroll
    for (int i = 0; i < 4; ++i) dst[i] = src[i];
  }
  {
    int r = t >> 1, half = t & 1;
    const short8* src = (const short8*)(wT + (size_t)r * 128 + half * 64);
    short8* dst = (short8*)(B_s + r * 136 + half * 64);
    #pragma unroll
    for (int i = 0; i < 8; ++i) dst[i] = src[i];
  }
  __syncthreads();
  f32x4 zero = {0.f, 0.f, 0.f, 0.f};
  f32x4 acc[2][4];
  #pragma unroll
  for (int tm = 0; tm < 2; ++tm)
    #pragma unroll
    for (int tn = 0; tn < 4; ++tn) acc[tm][tn] = zero;
  mfma_64x128(A_s, B_s, acc, wid, lane);
  const int m = lane & 15, kg = lane >> 4;
  const int ro = (wid & 1) * 32, co = (wid >> 1) * 64;
  #pragma unroll
  for (int tm = 0; tm < 2; ++tm)
    #pragma unroll
    for (int r = 0; r < 4; ++r) {
      int row = ro + tm * 16 + kg * 4 + r;
      size_t o = mbase + row;
      int nn = (int)(o & 63), wbox = (int)((o >> 6) & 511), bb = (int)(o >> 15);
      int gx = wbox >> 6, gy = (wbox >> 3) & 7, gz = wbox & 7;
      int ix = nn >> 4, iy = (nn >> 2) & 3, iz = nn & 3;
      int X = (gx * 4 + ix + 2) & 31, Y = (gy * 4 + iy + 2) & 31, Z = (gz * 4 + iz + 2) & 31;
      size_t orig = ((size_t)bb << 15) + (size_t)(X * 1024 + Y * 32 + Z);
      #pragma unroll
      for (int tn = 0; tn < 4; ++tn) {
        int col = co + tn * 16 + m;
        float v = acc[tm][tn][r] + proj_b[col];
        xws[orig * 128 + col] = 0.5f * v + inputs[orig * 128 + col];
      }
    }
}

// ---------------- fused LN2 + MLP (128->512 GELU ->128) + 0.5*h + x -> out ----------------
__global__ __launch_bounds__(256) void k_mlp(const float* __restrict__ x,
                                             const u16* __restrict__ w1T,
                                             const u16* __restrict__ w2T,
                                             const float* __restrict__ g2,
                                             const float* __restrict__ b2,
                                             const float* __restrict__ bb1,
                                             const float* __restrict__ bb2,
                                             float* __restrict__ out) {
  __shared__ __align__(16) u16 A_s[64 * 136];
  __shared__ __align__(16) u16 B1_s[64 * 136];
  __shared__ __align__(16) u16 H_s[64 * 72];
  __shared__ __align__(16) u16 B2_s[128 * 72];
  __shared__ float red[64][8];
  const int t = threadIdx.x, wid = t >> 6, lane = t & 63;
  const size_t mbase = (size_t)blockIdx.x * 64;
  {
    int r = t >> 2, seg = t & 3;
    const float4* x4 = (const float4*)(x + (mbase + r) * 128 + seg * 32);
    float vals[32];
    float s = 0.f, ss = 0.f;
    #pragma unroll
    for (int i = 0; i < 8; ++i) {
      float4 v = x4[i];
      vals[4 * i] = v.x; vals[4 * i + 1] = v.y; vals[4 * i + 2] = v.z; vals[4 * i + 3] = v.w;
      s += v.x + v.y + v.z + v.w;
      ss += v.x * v.x + v.y * v.y + v.z * v.z + v.w * v.w;
    }
    red[r][seg] = s; red[r][4 + seg] = ss;
    __syncthreads();
    float sum = red[r][0] + red[r][1] + red[r][2] + red[r][3];
    float sq = red[r][4] + red[r][5] + red[r][6] + red[r][7];
    float mean = sum * 0.0078125f;
    float var = sq * 0.0078125f - mean * mean;
    float rs = rsqrtf(var + 1e-5f);
    #pragma unroll
    for (int i = 0; i < 32; ++i) {
      int c = seg * 32 + i;
      A_s[r * 136 + c] = f2bf((vals[i] - mean) * rs * g2[c] + b2[c]);
    }
  }
  const int m = lane & 15, kg = lane >> 4;
  const int ro = (wid & 1) * 32;
  const int co2 = (wid >> 1) * 32;
  const int co = (wid >> 1) * 64;
  f32x4 zero = {0.f, 0.f, 0.f, 0.f};
  f32x4 acc[2][4];
  #pragma unroll
  for (int tm = 0; tm < 2; ++tm)
    #pragma unroll
    for (int tn = 0; tn < 4; ++tn) acc[tm][tn] = zero;
  for (int nt = 0; nt < 8; ++nt) {
    __syncthreads();
    {
      int r = t >> 2, seg = t & 3;
      const short8* src = (const short8*)(w1T + (size_t)(nt * 64 + r) * 128 + seg * 32);
      short8* dst = (short8*)(B1_s + r * 136 + seg * 32);
      #pragma unroll
      for (int i = 0; i < 4; ++i) dst[i] = src[i];
    }
    {
      int r = t >> 1, half = t & 1;
      const short8* src = (const short8*)(w2T + (size_t)r * 512 + nt * 64 + half * 32);
      short8* dst = (short8*)(B2_s + r * 72 + half * 32);
      #pragma unroll
      for (int i = 0; i < 4; ++i) dst[i] = src[i];
    }
    __syncthreads();
    f32x4 hacc[2][2];
    #pragma unroll
    for (int tm = 0; tm < 2; ++tm)
      #pragma unroll
      for (int tn = 0; tn < 2; ++tn) hacc[tm][tn] = zero;
    #pragma unroll
    for (int kc = 0; kc < 4; ++kc) {
      short8 a[2], b[2];
      #pragma unroll
      for (int tm = 0; tm < 2; ++tm)
        a[tm] = *(const short8*)(A_s + (ro + tm * 16 + m) * 136 + kc * 32 + kg * 8);
      #pragma unroll
      for (int tn = 0; tn < 2; ++tn)
        b[tn] = *(const short8*)(B1_s + (co2 + tn * 16 + m) * 136 + kc * 32 + kg * 8);
      #pragma unroll
      for (int tm = 0; tm < 2; ++tm)
        #pragma unroll
        for (int tn = 0; tn < 2; ++tn)
          hacc[tm][tn] = __builtin_amdgcn_mfma_f32_16x16x32_bf16(a[tm], b[tn], hacc[tm][tn], 0, 0, 0);
    }
    #pragma unroll
    for (int tm = 0; tm < 2; ++tm)
      #pragma unroll
      for (int tn = 0; tn < 2; ++tn)
        #pragma unroll
        for (int r = 0; r < 4; ++r) {
          int row = ro + tm * 16 + kg * 4 + r;
          int col = co2 + tn * 16 + m;
          float v = hacc[tm][tn][r] + bb1[nt * 64 + col];
          v = 0.5f * v * (1.f + erff(v * 0.7071067811865475f));
          H_s[row * 72 + col] = f2bf(v);
        }
    __syncthreads();
    #pragma unroll
    for (int kc = 0; kc < 2; ++kc) {
      short8 a[2], b[4];
      #pragma unroll
      for (int tm = 0; tm < 2; ++tm)
        a[tm] = *(const short8*)(H_s + (ro + tm * 16 + m) * 72 + kc * 32 + kg * 8);
      #pragma unroll
      for (int tn = 0; tn < 4; ++tn)
        b[tn] = *(const short8*)(B2_s + (co + tn * 16 + m) * 72 + kc * 32 + kg * 8);
      #pragma unroll
      for (int tm = 0; tm < 2; ++tm)
        #pragma unroll
        for (int tn = 0; tn < 4; ++tn)
          acc[tm][tn] = __builtin_amdgcn_mfma_f32_16x16x32_bf16(a[tm], b[tn], acc[tm][tn], 0, 0, 0);
    }
  }
  #pragma unroll
  for (int tm = 0; tm < 2; ++tm)
    #pragma unroll
    for (int tn = 0; tn < 4; ++tn)
      #pragma unroll
      for (int r = 0; r < 4; ++r) {
        int row = ro + tm * 16 + kg * 4 + r;
        int col = co + tn * 16 + m;
        size_t tok = mbase + row;
        float v = acc[tm][tn][r] + bb2[col];
        out[tok * 128 + col] = 0.5f * v + x[tok * 128 + col];
      }
}

extern "C" void kernel_launch(void* const* d_in, const int* in_sizes, int n_in,
                              void* d_out, int out_size, void* d_ws, size_t ws_size,
                              hipStream_t stream) {
  const float* inputs = (const float*)d_in[0];
  const float* qkv_w  = (const float*)d_in[1];
  const float* proj_w = (const float*)d_in[2];
  const float* proj_b = (const float*)d_in[3];
  const float* btab   = (const float*)d_in[4];
  const float* g1     = (const float*)d_in[5];
  const float* b1     = (const float*)d_in[6];
  const float* g2     = (const float*)d_in[7];
  const float* b2     = (const float*)d_in[8];
  const float* w1     = (const float*)d_in[9];
  const float* bb1    = (const float*)d_in[10];
  const float* w2     = (const float*)d_in[11];
  const float* bb2    = (const float*)d_in[12];
  float* out = (float*)d_out;

  char* ws = (char*)d_ws;
  u16* qkvT  = (u16*)(ws + 0);          // 384*128 bf16
  u16* projT = (u16*)(ws + 98304);      // 128*128
  u16* w1T   = (u16*)(ws + 131072);     // 512*128
  u16* w2T   = (u16*)(ws + 262144);     // 128*512
  u16* lnb   = (u16*)(ws + 393216);     // T*128 bf16 (reused as attn_out)
  u16* qkv   = (u16*)(ws + 393216 + 67108864);  // T*384 bf16 (reused as x fp32)
  u16* att   = lnb;                     // overlay: lnb dead after k_qkv
  float* xws = (float*)qkv;             // overlay: qkv dead after k_attn

  k_wprep<<<192, 256, 0, stream>>>(qkv_w, qkvT, 128, 384);
  k_wprep<<<64, 256, 0, stream>>>(proj_w, projT, 128, 128);
  k_wprep<<<256, 256, 0, stream>>>(w1, w1T, 128, 512);
  k_wprep<<<256, 256, 0, stream>>>(w2, w2T, 512, 128);

  k_ln1<<<65536, 256, 0, stream>>>(inputs, g1, b1, lnb);
  k_qkv<<<dim3(4096, 3), 256, 0, stream>>>(lnb, qkvT, qkv);
  k_attn<<<4096, 256, 0, stream>>>(qkv, btab, att);
  k_proj<<<4096, 256, 0, stream>>>(att, projT, proj_b, inputs, xws);
  k_mlp<<<4096, 256, 0, stream>>>(xws, w1T, w2T, g2, b2, bb1, bb2, out);
}

// Round 3
// 678.154 us; speedup vs baseline: 1.2621x; 1.0357x over previous
//
#include <hip/hip_runtime.h>
#include <hip/hip_bf16.h>

typedef unsigned short u16;
typedef unsigned int u32;
typedef __attribute__((ext_vector_type(8))) short short8;
typedef __attribute__((ext_vector_type(4))) float f32x4;

__device__ __forceinline__ u16 f2bf(float x) {
  __hip_bfloat16 h = __float2bfloat16(x);
  return *reinterpret_cast<u16*>(&h);
}
__device__ __forceinline__ float bflo(u32 u) { return __uint_as_float(u << 16); }
__device__ __forceinline__ float bfhi(u32 u) { return __uint_as_float(u & 0xffff0000u); }

// ---------------- weight transpose + cast: dst[n*K+k] = bf16(src[k*N+n]) ----------------
__global__ void k_wprep(const float* __restrict__ src, u16* __restrict__ dst, int K, int N) {
  int idx = blockIdx.x * 256 + threadIdx.x;
  if (idx >= K * N) return;
  int k = idx / N, n = idx - k * N;
  dst[n * K + k] = f2bf(src[idx]);
}

// ---------------- LN1 + roll(-2) + window partition -> bf16 [262144][128] ----------------
__global__ __launch_bounds__(256) void k_ln1(const float* __restrict__ in,
                                             const float* __restrict__ g1,
                                             const float* __restrict__ b1,
                                             u16* __restrict__ lnb) {
  int lane = threadIdx.x & 63;
  size_t o = (size_t)blockIdx.x * 4 + (threadIdx.x >> 6);
  int n = (int)(o & 63), wbox = (int)((o >> 6) & 511), b = (int)(o >> 15);
  int gx = wbox >> 6, gy = (wbox >> 3) & 7, gz = wbox & 7;
  int ix = n >> 4, iy = (n >> 2) & 3, iz = n & 3;
  int X = (gx * 4 + ix + 2) & 31, Y = (gy * 4 + iy + 2) & 31, Z = (gz * 4 + iz + 2) & 31;
  const float* row = in + (((size_t)b << 15) + (size_t)(X * 1024 + Y * 32 + Z)) * 128;
  float x0 = row[lane], x1 = row[lane + 64];
  float s = x0 + x1, ss = x0 * x0 + x1 * x1;
  #pragma unroll
  for (int off = 32; off > 0; off >>= 1) {
    s += __shfl_xor(s, off, 64);
    ss += __shfl_xor(ss, off, 64);
  }
  float mean = s * 0.0078125f;
  float var = ss * 0.0078125f - mean * mean;
  float rs = rsqrtf(var + 1e-5f);
  lnb[o * 128 + lane]      = f2bf((x0 - mean) * rs * g1[lane] + b1[lane]);
  lnb[o * 128 + lane + 64] = f2bf((x1 - mean) * rs * g1[lane + 64] + b1[lane + 64]);
}

// ---------------- shared 64x128-tile MFMA core: A_s [64][136], B_s(=W^T) [128][136] ----------------
__device__ __forceinline__ void mfma_64x128(const u16* A_s, const u16* B_s,
                                            f32x4 acc[2][4], int wid, int lane) {
  const int m = lane & 15, kg = lane >> 4;
  const int ro = (wid & 1) * 32, co = (wid >> 1) * 64;
  #pragma unroll
  for (int kc = 0; kc < 4; ++kc) {
    short8 a[2], b[4];
    #pragma unroll
    for (int tm = 0; tm < 2; ++tm)
      a[tm] = *(const short8*)(A_s + (ro + tm * 16 + m) * 136 + kc * 32 + kg * 8);
    #pragma unroll
    for (int tn = 0; tn < 4; ++tn)
      b[tn] = *(const short8*)(B_s + (co + tn * 16 + m) * 136 + kc * 32 + kg * 8);
    #pragma unroll
    for (int tm = 0; tm < 2; ++tm)
      #pragma unroll
      for (int tn = 0; tn < 4; ++tn)
        acc[tm][tn] = __builtin_amdgcn_mfma_f32_16x16x32_bf16(a[tm], b[tn], acc[tm][tn], 0, 0, 0);
  }
}

// ---------------- QKV GEMM: [T,128] x [128,384] -> bf16 qkv [T][384], q pre-scaled ----------------
__global__ __launch_bounds__(256) void k_qkv(const u16* __restrict__ lnb,
                                             const u16* __restrict__ wT,
                                             u16* __restrict__ qkv) {
  __shared__ __align__(16) u16 A_s[64 * 136];
  __shared__ __align__(16) u16 B_s[128 * 136];
  const int t = threadIdx.x, wid = t >> 6, lane = t & 63;
  const size_t mbase = (size_t)blockIdx.x * 64;
  const int n0 = blockIdx.y * 128;
  {
    int r = t >> 2, seg = t & 3;
    const short8* src = (const short8*)(lnb + (mbase + r) * 128 + seg * 32);
    short8* dst = (short8*)(A_s + r * 136 + seg * 32);
    #pragma unroll
    for (int i = 0; i < 4; ++i) dst[i] = src[i];
  }
  {
    int r = t >> 1, half = t & 1;
    const short8* src = (const short8*)(wT + (size_t)(n0 + r) * 128 + half * 64);
    short8* dst = (short8*)(B_s + r * 136 + half * 64);
    #pragma unroll
    for (int i = 0; i < 8; ++i) dst[i] = src[i];
  }
  __syncthreads();
  f32x4 zero = {0.f, 0.f, 0.f, 0.f};
  f32x4 acc[2][4];
  #pragma unroll
  for (int tm = 0; tm < 2; ++tm)
    #pragma unroll
    for (int tn = 0; tn < 4; ++tn) acc[tm][tn] = zero;
  mfma_64x128(A_s, B_s, acc, wid, lane);
  const int m = lane & 15, kg = lane >> 4;
  const int ro = (wid & 1) * 32, co = (wid >> 1) * 64;
  #pragma unroll
  for (int tm = 0; tm < 2; ++tm)
    #pragma unroll
    for (int tn = 0; tn < 4; ++tn)
      #pragma unroll
      for (int r = 0; r < 4; ++r) {
        int row = ro + tm * 16 + kg * 4 + r;
        int cc = n0 + co + tn * 16 + m;
        float v = acc[tm][tn][r];
        if (cc < 128) v *= 0.17677669529663687f;   // q * HD^-0.5
        qkv[(mbase + row) * 384 + cc] = f2bf(v);
      }
}

// ---------------- per-window attention, MFMA version: block=window, wave=head ----------------
__global__ __launch_bounds__(256) void k_attn(const u16* __restrict__ qkv,
                                              const float* __restrict__ btab,
                                              u16* __restrict__ att) {
  __shared__ float bias_s[4][128];               // [h][121] transposed bias table
  __shared__ __align__(16) u16 Vt_s[4][32][72];  // V^T per head: [d][key]
  __shared__ __align__(16) u16 P_s[4][64][72];   // exp(S-m) per head, unnormalized
  const int t = threadIdx.x;
  const int wv = t >> 6, lane = t & 63;
  const int m = lane & 15, q4 = lane >> 4;
  const int bw = blockIdx.x;
  const size_t base = (size_t)bw * 64;
  const int wbox = bw & 511;
  const int gx = wbox >> 6, gy = (wbox >> 3) & 7, gz = wbox & 7;

  for (int i = t; i < 484; i += 256) bias_s[i & 3][i >> 2] = btab[i];
  #pragma unroll
  for (int i = 0; i < 16; ++i) {
    int nn = i * 4 + wv;
    int ch = lane * 2;
    int hh = ch >> 5, d = ch & 31;
    u32 vv = *(const u32*)(qkv + (base + nn) * 384 + 256 + ch);
    Vt_s[hh][d][nn]     = (u16)(vv & 0xffffu);
    Vt_s[hh][d + 1][nn] = (u16)(vv >> 16);
  }

  short8 qf[4], kf[4];
  #pragma unroll
  for (int ti = 0; ti < 4; ++ti) {
    qf[ti] = *(const short8*)(qkv + (base + ti * 16 + m) * 384 + wv * 32 + q4 * 8);
    kf[ti] = *(const short8*)(qkv + (base + ti * 16 + m) * 384 + 128 + wv * 32 + q4 * 8);
  }

  f32x4 zero = {0.f, 0.f, 0.f, 0.f};
  f32x4 S[4][4];
  #pragma unroll
  for (int ti = 0; ti < 4; ++ti)
    #pragma unroll
    for (int tj = 0; tj < 4; ++tj) S[ti][tj] = zero;

  __syncthreads();

  #pragma unroll
  for (int ti = 0; ti < 4; ++ti)
    #pragma unroll
    for (int tj = 0; tj < 4; ++tj)
      S[ti][tj] = __builtin_amdgcn_mfma_f32_16x16x32_bf16(qf[ti], kf[tj], S[ti][tj], 0, 0, 0);

  int catx[4], caty[4], catz[4];
  #pragma unroll
  for (int a = 0; a < 4; ++a) {
    catx[a] = (gx < 7) ? 0 : ((a < 2) ? 1 : 2);
    caty[a] = (gy < 7) ? 0 : ((a < 2) ? 1 : 2);
    catz[a] = (gz < 7) ? 0 : ((a < 2) ? 1 : 2);
  }
  const int cy = (m >> 2) & 3, cz = m & 3;
  int labc[4], labr[16];
  #pragma unroll
  for (int tj = 0; tj < 4; ++tj) labc[tj] = catx[tj] * 9 + caty[cy] * 3 + catz[cz];
  #pragma unroll
  for (int ti = 0; ti < 4; ++ti)
    #pragma unroll
    for (int r = 0; r < 4; ++r) labr[ti * 4 + r] = catx[ti] * 9 + caty[q4] * 3 + catz[r];

  #pragma unroll
  for (int ti = 0; ti < 4; ++ti)
    #pragma unroll
    for (int tj = 0; tj < 4; ++tj) {
      int K0 = 11 * (ti - tj + 3) + (q4 + 3 - cy) + (3 - cz);
      #pragma unroll
      for (int r = 0; r < 4; ++r) {
        float v = S[ti][tj][r] + bias_s[wv][K0 + r];
        if (labr[ti * 4 + r] != labc[tj]) v -= 100.f;
        S[ti][tj][r] = v;
      }
    }

  float mx[16], sm[16];
  #pragma unroll
  for (int ti = 0; ti < 4; ++ti)
    #pragma unroll
    for (int r = 0; r < 4; ++r)
      mx[ti * 4 + r] = fmaxf(fmaxf(S[ti][0][r], S[ti][1][r]), fmaxf(S[ti][2][r], S[ti][3][r]));
  #pragma unroll
  for (int off = 1; off < 16; off <<= 1)
    #pragma unroll
    for (int i = 0; i < 16; ++i) mx[i] = fmaxf(mx[i], __shfl_xor(mx[i], off, 64));
  #pragma unroll
  for (int ti = 0; ti < 4; ++ti)
    #pragma unroll
    for (int r = 0; r < 4; ++r) {
      float e0 = __expf(S[ti][0][r] - mx[ti * 4 + r]);
      float e1 = __expf(S[ti][1][r] - mx[ti * 4 + r]);
      float e2 = __expf(S[ti][2][r] - mx[ti * 4 + r]);
      float e3 = __expf(S[ti][3][r] - mx[ti * 4 + r]);
      S[ti][0][r] = e0; S[ti][1][r] = e1; S[ti][2][r] = e2; S[ti][3][r] = e3;
      sm[ti * 4 + r] = (e0 + e1) + (e2 + e3);
    }
  #pragma unroll
  for (int off = 1; off < 16; off <<= 1)
    #pragma unroll
    for (int i = 0; i < 16; ++i) sm[i] += __shfl_xor(sm[i], off, 64);
  #pragma unroll
  for (int i = 0; i < 16; ++i) sm[i] = 1.f / sm[i];

  #pragma unroll
  for (int ti = 0; ti < 4; ++ti)
    #pragma unroll
    for (int tj = 0; tj < 4; ++tj)
      #pragma unroll
      for (int r = 0; r < 4; ++r)
        P_s[wv][ti * 16 + q4 * 4 + r][tj * 16 + m] = f2bf(S[ti][tj][r]);

  f32x4 O[4][2];
  #pragma unroll
  for (int ti = 0; ti < 4; ++ti)
    #pragma unroll
    for (int tv = 0; tv < 2; ++tv) O[ti][tv] = zero;
  #pragma unroll
  for (int ks = 0; ks < 2; ++ks) {
    short8 pa[4], vb[2];
    #pragma unroll
    for (int ti = 0; ti < 4; ++ti)
      pa[ti] = *(const short8*)&P_s[wv][ti * 16 + m][ks * 32 + q4 * 8];
    #pragma unroll
    for (int tv = 0; tv < 2; ++tv)
      vb[tv] = *(const short8*)&Vt_s[wv][tv * 16 + m][ks * 32 + q4 * 8];
    #pragma unroll
    for (int ti = 0; ti < 4; ++ti)
      #pragma unroll
      for (int tv = 0; tv < 2; ++tv)
        O[ti][tv] = __builtin_amdgcn_mfma_f32_16x16x32_bf16(pa[ti], vb[tv], O[ti][tv], 0, 0, 0);
  }

  #pragma unroll
  for (int ti = 0; ti < 4; ++ti)
    #pragma unroll
    for (int tv = 0; tv < 2; ++tv)
      #pragma unroll
      for (int r = 0; r < 4; ++r) {
        int n = ti * 16 + q4 * 4 + r;
        att[(base + n) * 128 + wv * 32 + tv * 16 + m] = f2bf(O[ti][tv][r] * sm[ti * 4 + r]);
      }
}

// ---------------- proj GEMM + reverse-partition/unshift scatter + 0.5*out + inputs -> x (fp32) ----------------
__global__ __launch_bounds__(256) void k_proj(const u16* __restrict__ att,
                                              const u16* __restrict__ wT,
                                              const float* __restrict__ proj_b,
                                              const float* __restrict__ inputs,
                                              float* __restrict__ xws) {
  __shared__ __align__(16) u16 A_s[64 * 136];
  __shared__ __align__(16) u16 B_s[128 * 136];
  const int t = threadIdx.x, wid = t >> 6, lane = t & 63;
  const size_t mbase = (size_t)blockIdx.x * 64;
  {
    int r = t >> 2, seg = t & 3;
    const short8* src = (const short8*)(att + (mbase + r) * 128 + seg * 32);
    short8* dst = (short8*)(A_s + r * 136 + seg * 32);
    #pragma unroll
    for (int i = 0; i < 4; ++i) dst[i] = src[i];
  }
  {
    int r = t >> 1, half = t & 1;
    const short8* src = (const short8*)(wT + (size_t)r * 128 + half * 64);
    short8* dst = (short8*)(B_s + r * 136 + half * 64);
    #pragma unroll
    for (int i = 0; i < 8; ++i) dst[i] = src[i];
  }
  __syncthreads();
  f32x4 zero = {0.f, 0.f, 0.f, 0.f};
  f32x4 acc[2][4];
  #pragma unroll
  for (int tm = 0; tm < 2; ++tm)
    #pragma unroll
    for (int tn = 0; tn < 4; ++tn) acc[tm][tn] = zero;
  mfma_64x128(A_s, B_s, acc, wid, lane);
  const int m = lane & 15, kg = lane >> 4;
  const int ro = (wid & 1) * 32, co = (wid >> 1) * 64;
  #pragma unroll
  for (int tm = 0; tm < 2; ++tm)
    #pragma unroll
    for (int r = 0; r < 4; ++r) {
      int row = ro + tm * 16 + kg * 4 + r;
      size_t o = mbase + row;
      int nn = (int)(o & 63), wbox = (int)((o >> 6) & 511), bb = (int)(o >> 15);
      int gx = wbox >> 6, gy = (wbox >> 3) & 7, gz = wbox & 7;
      int ix = nn >> 4, iy = (nn >> 2) & 3, iz = nn & 3;
      int X = (gx * 4 + ix + 2) & 31, Y = (gy * 4 + iy + 2) & 31, Z = (gz * 4 + iz + 2) & 31;
      size_t orig = ((size_t)bb << 15) + (size_t)(X * 1024 + Y * 32 + Z);
      #pragma unroll
      for (int tn = 0; tn < 4; ++tn) {
        int col = co + tn * 16 + m;
        float v = acc[tm][tn][r] + proj_b[col];
        xws[orig * 128 + col] = 0.5f * v + inputs[orig * 128 + col];
      }
    }
}

// ---------------- fused LN2 + MLP, restructured: A-frags in regs, wave-private H, 3 blocks/CU ----------------
__global__ __launch_bounds__(256) void k_mlp(const float* __restrict__ x,
                                             const u16* __restrict__ w1T,
                                             const u16* __restrict__ w2T,
                                             const float* __restrict__ g2,
                                             const float* __restrict__ b2,
                                             const float* __restrict__ bb1,
                                             const float* __restrict__ bb2,
                                             float* __restrict__ out) {
  // LDS layout (53248 B total -> 3 blocks/CU):
  //   [0,17408)      B1_s [64][136]  (w1 tile; pre-loop overlay: red[64][8] floats)
  //   [17408,35840)  B2_s [128][72]  (w2 tile)
  //   [35840,53248)  A_s  [64][136]  (LN2 out; reused as H [64][72] inside loop)
  __shared__ __align__(16) char lds[53248];
  u16* B1_s = (u16*)lds;
  u16* B2_s = (u16*)(lds + 17408);
  u16* A_s  = (u16*)(lds + 35840);
  u16* H_s  = (u16*)(lds + 35840);
  float* red = (float*)lds;

  const int t = threadIdx.x, wid = t >> 6, lane = t & 63;
  const int m = lane & 15, q4 = lane >> 4;
  const size_t mbase = (size_t)blockIdx.x * 64;

  // ---- LN2: entirely wave-local (rows 16w..16w+15 handled by wave w) ----
  {
    int r = t >> 2, seg = t & 3;
    const float4* x4 = (const float4*)(x + (mbase + r) * 128 + seg * 32);
    float vals[32];
    float s = 0.f, ss = 0.f;
    #pragma unroll
    for (int i = 0; i < 8; ++i) {
      float4 v = x4[i];
      vals[4 * i] = v.x; vals[4 * i + 1] = v.y; vals[4 * i + 2] = v.z; vals[4 * i + 3] = v.w;
      s += v.x + v.y + v.z + v.w;
      ss += v.x * v.x + v.y * v.y + v.z * v.z + v.w * v.w;
    }
    red[r * 8 + seg] = s; red[r * 8 + 4 + seg] = ss;
    float sum = red[r * 8 + 0] + red[r * 8 + 1] + red[r * 8 + 2] + red[r * 8 + 3];
    float sq  = red[r * 8 + 4] + red[r * 8 + 5] + red[r * 8 + 6] + red[r * 8 + 7];
    float mean = sum * 0.0078125f;
    float var = sq * 0.0078125f - mean * mean;
    float rs = rsqrtf(var + 1e-5f);
    #pragma unroll
    for (int i = 0; i < 32; ++i) {
      int c = seg * 32 + i;
      A_s[r * 136 + c] = f2bf((vals[i] - mean) * rs * g2[c] + b2[c]);
    }
  }
  // ---- A fragments -> registers (wave-local rows; held for whole loop) ----
  short8 af[4];
  #pragma unroll
  for (int kc = 0; kc < 4; ++kc)
    af[kc] = *(const short8*)(A_s + (wid * 16 + m) * 136 + kc * 32 + q4 * 8);

  f32x4 zero = {0.f, 0.f, 0.f, 0.f};
  f32x4 acc[8];
  #pragma unroll
  for (int tn = 0; tn < 8; ++tn) acc[tn] = zero;

  for (int nt = 0; nt < 8; ++nt) {
    __syncthreads();   // prior-iter B reads (and pre-loop red/A-frag reads) done
    {
      int r = t >> 2, seg = t & 3;
      const short8* src = (const short8*)(w1T + (size_t)(nt * 64 + r) * 128 + seg * 32);
      short8* dst = (short8*)(B1_s + r * 136 + seg * 32);
      #pragma unroll
      for (int i = 0; i < 4; ++i) dst[i] = src[i];
    }
    {
      int r = t >> 1, half = t & 1;
      const short8* src = (const short8*)(w2T + (size_t)r * 512 + nt * 64 + half * 32);
      short8* dst = (short8*)(B2_s + r * 72 + half * 32);
      #pragma unroll
      for (int i = 0; i < 4; ++i) dst[i] = src[i];
    }
    __syncthreads();
    // GEMM1: 16 rows x 64 cols per wave
    f32x4 hacc[4];
    #pragma unroll
    for (int tn = 0; tn < 4; ++tn) hacc[tn] = zero;
    #pragma unroll
    for (int kc = 0; kc < 4; ++kc) {
      short8 b[4];
      #pragma unroll
      for (int tn = 0; tn < 4; ++tn)
        b[tn] = *(const short8*)(B1_s + (tn * 16 + m) * 136 + kc * 32 + q4 * 8);
      #pragma unroll
      for (int tn = 0; tn < 4; ++tn)
        hacc[tn] = __builtin_amdgcn_mfma_f32_16x16x32_bf16(af[kc], b[tn], hacc[tn], 0, 0, 0);
    }
    // GELU -> wave-private H rows (no barrier: producer == consumer wave)
    #pragma unroll
    for (int tn = 0; tn < 4; ++tn)
      #pragma unroll
      for (int r = 0; r < 4; ++r) {
        int rl = q4 * 4 + r;
        float v = hacc[tn][r] + bb1[nt * 64 + tn * 16 + m];
        v = 0.5f * v * (1.f + erff(v * 0.7071067811865475f));
        H_s[(wid * 16 + rl) * 72 + tn * 16 + m] = f2bf(v);
      }
    // GEMM2: 16 rows x 128 cols per wave, accumulate
    #pragma unroll
    for (int kc2 = 0; kc2 < 2; ++kc2) {
      short8 pa = *(const short8*)(H_s + (wid * 16 + m) * 72 + kc2 * 32 + q4 * 8);
      #pragma unroll
      for (int tn = 0; tn < 8; ++tn) {
        short8 b = *(const short8*)(B2_s + (tn * 16 + m) * 72 + kc2 * 32 + q4 * 8);
        acc[tn] = __builtin_amdgcn_mfma_f32_16x16x32_bf16(pa, b, acc[tn], 0, 0, 0);
      }
    }
  }
  // epilogue: 0.5*mlp + x
  #pragma unroll
  for (int tn = 0; tn < 8; ++tn)
    #pragma unroll
    for (int r = 0; r < 4; ++r) {
      int row = wid * 16 + q4 * 4 + r;
      int col = tn * 16 + m;
      size_t tok = mbase + row;
      float v = acc[tn][r] + bb2[col];
      out[tok * 128 + col] = 0.5f * v + x[tok * 128 + col];
    }
}

extern "C" void kernel_launch(void* const* d_in, const int* in_sizes, int n_in,
                              void* d_out, int out_size, void* d_ws, size_t ws_size,
                              hipStream_t stream) {
  const float* inputs = (const float*)d_in[0];
  const float* qkv_w  = (const float*)d_in[1];
  const float* proj_w = (const float*)d_in[2];
  const float* proj_b = (const float*)d_in[3];
  const float* btab   = (const float*)d_in[4];
  const float* g1     = (const float*)d_in[5];
  const float* b1     = (const float*)d_in[6];
  const float* g2     = (const float*)d_in[7];
  const float* b2     = (const float*)d_in[8];
  const float* w1     = (const float*)d_in[9];
  const float* bb1    = (const float*)d_in[10];
  const float* w2     = (const float*)d_in[11];
  const float* bb2    = (const float*)d_in[12];
  float* out = (float*)d_out;

  char* ws = (char*)d_ws;
  u16* qkvT  = (u16*)(ws + 0);          // 384*128 bf16
  u16* projT = (u16*)(ws + 98304);      // 128*128
  u16* w1T   = (u16*)(ws + 131072);     // 512*128
  u16* w2T   = (u16*)(ws + 262144);     // 128*512
  u16* lnb   = (u16*)(ws + 393216);     // T*128 bf16 (reused as attn_out)
  u16* qkv   = (u16*)(ws + 393216 + 67108864);  // T*384 bf16 (reused as x fp32)
  u16* att   = lnb;                     // overlay: lnb dead after k_qkv
  float* xws = (float*)qkv;             // overlay: qkv dead after k_attn

  k_wprep<<<192, 256, 0, stream>>>(qkv_w, qkvT, 128, 384);
  k_wprep<<<64, 256, 0, stream>>>(proj_w, projT, 128, 128);
  k_wprep<<<256, 256, 0, stream>>>(w1, w1T, 128, 512);
  k_wprep<<<256, 256, 0, stream>>>(w2, w2T, 512, 128);

  k_ln1<<<65536, 256, 0, stream>>>(inputs, g1, b1, lnb);
  k_qkv<<<dim3(4096, 3), 256, 0, stream>>>(lnb, qkvT, qkv);
  k_attn<<<4096, 256, 0, stream>>>(qkv, btab, att);
  k_proj<<<4096, 256, 0, stream>>>(att, projT, proj_b, inputs, xws);
  k_mlp<<<4096, 256, 0, stream>>>(xws, w1T, w2T, g2, b2, bb1, bb2, out);
}